// Round 10
// baseline (1801.127 us; speedup 1.0000x reference)
//
#include <hip/hip_runtime.h>
#include <math.h>

#define N_NODE 4096
#define N_EDGE 262144
#define E_TOT (N_EDGE + N_NODE)
#define DD 64
#define NL 3
#define NG 64

typedef __fp16 h2_t __attribute__((ext_vector_type(2)));
union H2x4 { uint4 u; h2_t h[4]; };

__device__ __forceinline__ void atomAddF(float* p, float v) {
#if defined(__HIP_PLATFORM_AMD__)
  unsafeAtomicAdd(p, v);
#else
  atomicAdd(p, v);
#endif
}

// BN with training-mode stats; st==null -> identity passthrough.
__device__ __forceinline__ float bn_eval(float z, const float* st, const float* g,
                                         const float* b, int d, bool relu) {
  if (st == nullptr) return z;
  const float invN = 2.44140625e-4f;  // 1/4096
  float mu = st[d] * invN;
  float var = fmaf(st[64 + d], invN, -mu * mu);
  float v = (z - mu) * rsqrtf(var + 1e-5f) * g[d] + b[d];
  return relu ? fmaxf(v, 0.f) : v;
}

// ---------------- CSR build ----------------
__global__ void csr_count_kernel(const int* __restrict__ ei, int* __restrict__ cnt) {
  int e = blockIdx.x * blockDim.x + threadIdx.x;
  if (e >= E_TOT) return;
  int dst = (e < N_EDGE) ? ei[N_EDGE + e] : (e - N_EDGE);
  atomicAdd(&cnt[dst], 1);
}

__global__ void csr_scan_kernel(const int* __restrict__ cnt, int* __restrict__ row_ptr,
                                int* __restrict__ nextp) {
  __shared__ int ps[256];
  __shared__ int ps2[257];
  int t = threadIdx.x;
  int base = t * 16;
  int loc[16];
  int s = 0;
#pragma unroll
  for (int k = 0; k < 16; ++k) { loc[k] = s; s += cnt[base + k]; }
  ps[t] = s;
  __syncthreads();
  if (t == 0) {
    int a = 0;
    for (int u = 0; u < 256; ++u) { ps2[u] = a; a += ps[u]; }
    ps2[256] = a;
  }
  __syncthreads();
  int off = ps2[t];
#pragma unroll
  for (int k = 0; k < 16; ++k) {
    int v = off + loc[k];
    row_ptr[base + k] = v;
    nextp[base + k] = v;
  }
  if (t == 0) row_ptr[N_NODE] = ps2[256];
}

__global__ void csr_fill_kernel(const int* __restrict__ ei, int* __restrict__ nextp,
                                int* __restrict__ csr_src) {
  int e = blockIdx.x * blockDim.x + threadIdx.x;
  if (e >= E_TOT) return;
  int src, dst;
  if (e < N_EDGE) { src = ei[e]; dst = ei[N_EDGE + e]; }
  else { src = dst = e - N_EDGE; }
  int pos = atomicAdd(&nextp[dst], 1);
  csr_src[pos] = src;
}

// ---------------- build combined weights (once) ----------------
__global__ void build_w_kernel(const float* __restrict__ wl, const float* __restrict__ bl,
                               const float* __restrict__ wr, const float* __restrict__ br,
                               const float* __restrict__ win, const float* __restrict__ bin,
                               const float* __restrict__ wout,
                               float* __restrict__ cw, float* __restrict__ cbias,
                               float* __restrict__ tout) {
  int idx = blockIdx.x * blockDim.x + threadIdx.x;
  if (idx < NL * 64 * 320) {
    int l = idx / 20480, rem = idx % 20480;
    int k = rem / 320, j = rem % 320;
    float v;
    if (j < 64) v = wl[l * 4096 + k * 64 + j];
    else if (j < 128) v = wr[l * 4096 + k * 64 + (j - 64)];
    else v = win[l * 12288 + (j - 128) * 64 + k];
    cw[idx] = v;
  }
  if (idx < NL * 320) {
    int l = idx / 320, j = idx % 320;
    float v;
    if (j < 64) v = bl[l * 64 + j];
    else if (j < 128) v = br[l * 64 + (j - 64)];
    else v = bin[l * 192 + (j - 128)];
    cbias[idx] = v;
  }
  if (idx < NL * 4096) {
    int l = idx / 4096, rem = idx % 4096;
    int k = rem / 64, j = rem % 64;
    tout[l * 4096 + k * 64 + j] = wout[l * 4096 + j * 64 + k];
  }
}

// ---------------- fused linear engine ----------------
struct LinP {
  const float *A, *A2, *W, *bias;
  float *C, *C2;
  const float *i_st, *i_g, *i_b, *i2_st, *i2_g, *i2_b;
  const float *R, *R2, *r_st, *r_g, *r_b, *r2_st, *r2_g, *r2_b;
  float *accO_w, *accS_w;
  int* kmax_clr;
  float* spart;
};

// TIN: 0 plain A[row*KK+k]; 1 bn3+relu(A); 2 bn1(A)+bn2(A2); 3 attn-norm from accO/accS (+clean)
// TRES: 0 none; 1 bn3+relu(R); 2 bn1(R)+bn2(R2)
// ACT: 0 none; 1 gelu; 2 relu  (applied before residual)
template<int NC, int KK, int TIN, int TRES, int ACT, bool SPLIT, bool STOUT, bool KCLR>
__global__ void lin_kernel(LinP P) {
  constexpr int BLK = (NC < 256) ? 256 : NC;
  constexpr int G = BLK / NC;
  constexpr int BR = 16;
  constexpr int RPT = BR / G;
  constexpr int LDA = (KK % 4 == 0) ? KK + 4 : KK;
  __shared__ __align__(16) float sA[BR * LDA];
  __shared__ float sred[4 * 128];
  const int tid = threadIdx.x;
  const int row0 = blockIdx.x * BR;

  for (int idx = tid; idx < BR * KK; idx += BLK) {
    int r, k;
    if constexpr (TIN == 3) { r = idx & 15; k = idx >> 4; }
    else { r = idx / KK; k = idx - r * KK; }
    int row = row0 + r;
    float v;
    if constexpr (TIN == 0) v = P.A[row * KK + k];
    else if constexpr (TIN == 1) v = bn_eval(P.A[row * 64 + k], P.i_st, P.i_g, P.i_b, k, true);
    else if constexpr (TIN == 2) v = bn_eval(P.A[row * 64 + k], P.i_st, P.i_g, P.i_b, k, false)
                                   + bn_eval(P.A2[row * 64 + k], P.i2_st, P.i2_g, P.i2_b, k, false);
    else {
      float num = P.accO_w[k * 4096 + row];
      float den = P.accS_w[(k >> 4) * 4096 + row];
      v = num / den;
      P.accO_w[k * 4096 + row] = 0.f;  // same-thread RMW: safe
      // accS zeroing deferred to after __syncthreads() (round-6 race fix).
    }
    sA[r * LDA + k] = v;
  }
  if constexpr (KCLR) { if (blockIdx.x == 0 && tid < 4) P.kmax_clr[tid] = 0; }

  int j, rg;
  if constexpr (G == 1) { j = tid; rg = 0; }
  else { j = tid & (NC - 1); rg = tid >> (NC == 64 ? 6 : 7); }

  float w[KK];
#pragma unroll
  for (int k = 0; k < KK; ++k) w[k] = P.W[k * NC + j];
  float bs = P.bias[j];
  float acc[RPT];
#pragma unroll
  for (int rr = 0; rr < RPT; ++rr) acc[rr] = bs;
  __syncthreads();

  if constexpr (TIN == 3) {
    // all den reads completed before the barrier; rows are block-private.
    if (tid < 64) P.accS_w[(tid >> 4) * 4096 + row0 + (tid & 15)] = 0.f;
  }

  if constexpr (KK % 4 == 0) {
#pragma unroll
    for (int rr = 0; rr < RPT; ++rr) {
      const float* ap = sA + (rg * RPT + rr) * LDA;
#pragma unroll
      for (int k4 = 0; k4 < KK / 4; ++k4) {
        float4 a = *(const float4*)(ap + 4 * k4);
        acc[rr] = fmaf(a.x, w[4 * k4 + 0], acc[rr]);
        acc[rr] = fmaf(a.y, w[4 * k4 + 1], acc[rr]);
        acc[rr] = fmaf(a.z, w[4 * k4 + 2], acc[rr]);
        acc[rr] = fmaf(a.w, w[4 * k4 + 3], acc[rr]);
      }
    }
  } else {
#pragma unroll
    for (int rr = 0; rr < RPT; ++rr) {
      const float* ap = sA + (rg * RPT + rr) * LDA;
#pragma unroll
      for (int k = 0; k < KK; ++k) acc[rr] = fmaf(ap[k], w[k], acc[rr]);
    }
  }

  float lsum = 0.f, lsq = 0.f;
#pragma unroll
  for (int rr = 0; rr < RPT; ++rr) {
    int row = row0 + rg * RPT + rr;
    float v = acc[rr];
    if constexpr (ACT == 1) v = 0.5f * v * (1.0f + erff(v * 0.70710678118654752f));
    else if constexpr (ACT == 2) v = fmaxf(v, 0.0f);
    if constexpr (TRES == 1) v += bn_eval(P.R[row * 64 + j], P.r_st, P.r_g, P.r_b, j, true);
    else if constexpr (TRES == 2) v += bn_eval(P.R[row * 64 + j], P.r_st, P.r_g, P.r_b, j, false)
                                     + bn_eval(P.R2[row * 64 + j], P.r2_st, P.r2_g, P.r2_b, j, false);
    if constexpr (SPLIT) {
      if (j < 128) P.C[row * 128 + j] = v;
      else P.C2[row * 192 + (j - 128)] = v;
    } else {
      P.C[row * NC + j] = v;
    }
    if constexpr (STOUT) { lsum += v; lsq = fmaf(v, v, lsq); }
  }
  if constexpr (STOUT) {
    sred[rg * 128 + j] = lsum;
    sred[rg * 128 + 64 + j] = lsq;
    __syncthreads();
    if (rg == 0) {
      float s0 = 0.f, q0 = 0.f;
#pragma unroll
      for (int g2 = 0; g2 < G; ++g2) { s0 += sred[g2 * 128 + j]; q0 += sred[g2 * 128 + 64 + j]; }
      P.spart[blockIdx.x * 128 + j] = s0;
      P.spart[blockIdx.x * 128 + 64 + j] = q0;
    }
  }
}

// ---------------- stats partial reduce: grid (128, nsets), block 64 ----------------
__global__ void red_kernel(const float* __restrict__ p1, float* __restrict__ s1,
                           const float* __restrict__ p2, float* __restrict__ s2) {
  const float* p = blockIdx.y ? p2 : p1;
  float* s = blockIdx.y ? s2 : s1;
  int c = blockIdx.x;
  float a = 0.f;
  for (int bb = threadIdx.x; bb < 256; bb += 64) a += p[bb * 128 + c];
#pragma unroll
  for (int off = 32; off; off >>= 1) a += __shfl_xor(a, off, 64);
  if (threadIdx.x == 0) s[c] = a;
}

// ---------------- GATv2 aggregate: 16 waves/block, emits st1 partials ----------------
__global__ __launch_bounds__(1024) void gat_agg_kernel(
    const float* __restrict__ state, const float* __restrict__ st3,
    const float* __restrict__ g3, const float* __restrict__ b3,
    const float* __restrict__ xlr, const float* __restrict__ att,
    const float* __restrict__ gbias, const int* __restrict__ row_ptr,
    const int* __restrict__ csr_src, float* __restrict__ z1, float* __restrict__ spart) {
  __shared__ float red[16][64];
  int w = threadIdx.x >> 6, lane = threadIdx.x & 63;
  int i = blockIdx.x * 16 + w;
  float xr_d = xlr[i * 128 + 64 + lane];
  float att_d = att[lane];
  float m = -INFINITY, s = 0.f, acc = 0.f;
  int e0 = row_ptr[i], e1 = row_ptr[i + 1];
  for (int e = e0; e < e1; ++e) {
    int src = csr_src[e];
    float xl_d = xlr[src * 128 + lane];
    float vv = xl_d + xr_d;
    float lr = (vv > 0.f) ? vv : 0.2f * vv;
    float p = lr * att_d;
#pragma unroll
    for (int off = 32; off; off >>= 1) p += __shfl_xor(p, off, 64);
    float nm = fmaxf(m, p);
    float corr = __expf(m - nm);
    float wt = __expf(p - nm);
    s = s * corr + wt;
    acc = acc * corr + wt * xl_d;
    m = nm;
  }
  float resid = bn_eval(state[i * 64 + lane], st3, g3, b3, lane, true);
  float val = resid + gbias[lane] + acc / s;
  z1[i * 64 + lane] = val;
  red[w][lane] = val;
  __syncthreads();
  if (w == 0) {
    float ss = 0.f, qq = 0.f;
#pragma unroll
    for (int u = 0; u < 16; ++u) { float v = red[u][lane]; ss += v; qq = fmaf(v, v, qq); }
    spart[blockIdx.x * 128 + lane] = ss;
    spart[blockIdx.x * 128 + 64 + lane] = qq;
  }
}

// ---------------- K row-norm max per head ----------------
__global__ void knorm_kernel(const float* __restrict__ qkv, int* __restrict__ kmax) {
  __shared__ int lmax[4];
  int tid = threadIdx.x;
  if (tid < 4) lmax[tid] = 0;
  __syncthreads();
  int idx = blockIdx.x * 256 + tid;
  int j = idx >> 2, h = idx & 3;
  const float* kr = qkv + (size_t)j * 192 + 64 + h * 16;
  float n2 = 0.f;
#pragma unroll
  for (int c = 0; c < 16; ++c) { float v = kr[c]; n2 = fmaf(v, v, n2); }
  atomicMax(&lmax[h], __float_as_int(sqrtf(n2)));
  __syncthreads();
  if (tid < 4) atomicMax(&kmax[tid], lmax[tid]);
}

// ---------------- flash attention f16-dot2, fixed shift, j-split 8 ----------------
#define TJ 256
__global__ void attn_kernel(const float* __restrict__ qkv, const int* __restrict__ kmax,
                            float* __restrict__ accS, float* __restrict__ accO) {
  __shared__ __align__(16) float smem[4416];
  uint4* kt = (uint4*)smem;
  uint4* vt = (uint4*)(smem + 2048);
  int h = blockIdx.y, js = blockIdx.z;
  int i0 = blockIdx.x * 64;
  int r = threadIdx.x & 63;
  int gq = threadIdx.x >> 6;
  int i = i0 + r;
  float qf[16];
  const float* qr = qkv + (size_t)i * 192 + h * 16;
#pragma unroll
  for (int c = 0; c < 16; ++c) qf[c] = qr[c] * 0.25f;
  float qn2 = 0.f;
#pragma unroll
  for (int c = 0; c < 16; ++c) qn2 = fmaf(qf[c], qf[c], qn2);
  float m = sqrtf(qn2) * __int_as_float(kmax[h]);
  h2_t q2[8];
#pragma unroll
  for (int c = 0; c < 8; ++c) q2[c] = __builtin_amdgcn_cvt_pkrtz(qf[2 * c], qf[2 * c + 1]);
  float s = 0.f;
  float acc[16];
#pragma unroll
  for (int c = 0; c < 16; ++c) acc[c] = 0.f;

  for (int t = 0; t < 2; ++t) {
    int j0 = js * 512 + t * TJ;
    __syncthreads();
    {
      int jj = threadIdx.x;
      const float* kr = qkv + (size_t)(j0 + jj) * 192 + 64 + h * 16;
      float4 a = *(const float4*)kr, b = *(const float4*)(kr + 4);
      float4 c4f = *(const float4*)(kr + 8), d4 = *(const float4*)(kr + 12);
      H2x4 w0, w1;
      w0.h[0] = __builtin_amdgcn_cvt_pkrtz(a.x, a.y); w0.h[1] = __builtin_amdgcn_cvt_pkrtz(a.z, a.w);
      w0.h[2] = __builtin_amdgcn_cvt_pkrtz(b.x, b.y); w0.h[3] = __builtin_amdgcn_cvt_pkrtz(b.z, b.w);
      w1.h[0] = __builtin_amdgcn_cvt_pkrtz(c4f.x, c4f.y); w1.h[1] = __builtin_amdgcn_cvt_pkrtz(c4f.z, c4f.w);
      w1.h[2] = __builtin_amdgcn_cvt_pkrtz(d4.x, d4.y); w1.h[3] = __builtin_amdgcn_cvt_pkrtz(d4.z, d4.w);
      kt[jj * 2] = w0.u; kt[jj * 2 + 1] = w1.u;
      for (int id = threadIdx.x; id < 512; id += 256) {
        int c4 = id & 3, jp = id >> 2;
        const float* va = qkv + (size_t)(j0 + 2 * jp) * 192 + 128 + h * 16 + c4 * 4;
        float4 A = *(const float4*)va, B = *(const float4*)(va + 192);
        H2x4 w;
        w.h[0] = __builtin_amdgcn_cvt_pkrtz(A.x, B.x); w.h[1] = __builtin_amdgcn_cvt_pkrtz(A.y, B.y);
        w.h[2] = __builtin_amdgcn_cvt_pkrtz(A.z, B.z); w.h[3] = __builtin_amdgcn_cvt_pkrtz(A.w, B.w);
        vt[c4 * 128 + jp] = w.u;
      }
    }
    __syncthreads();
    for (int jp = gq; jp < 128; jp += 4) {
      H2x4 ka0, ka1, kb0, kb1;
      ka0.u = kt[jp * 4 + 0]; ka1.u = kt[jp * 4 + 1];
      kb0.u = kt[jp * 4 + 2]; kb1.u = kt[jp * 4 + 3];
      float sa = 0.f, sb = 0.f;
#pragma unroll
      for (int c = 0; c < 4; ++c) {
        sa = __builtin_amdgcn_fdot2(q2[c], ka0.h[c], sa, false);
        sb = __builtin_amdgcn_fdot2(q2[c], kb0.h[c], sb, false);
      }
#pragma unroll
      for (int c = 0; c < 4; ++c) {
        sa = __builtin_amdgcn_fdot2(q2[4 + c], ka1.h[c], sa, false);
        sb = __builtin_amdgcn_fdot2(q2[4 + c], kb1.h[c], sb, false);
      }
      float pa = __expf(sa - m), pb = __expf(sb - m);
      s += pa + pb;
      h2_t pp = __builtin_amdgcn_cvt_pkrtz(pa, pb);
      H2x4 v0, v1, v2, v3;
      v0.u = vt[jp]; v1.u = vt[128 + jp]; v2.u = vt[256 + jp]; v3.u = vt[384 + jp];
#pragma unroll
      for (int c = 0; c < 4; ++c) {
        acc[c]      = __builtin_amdgcn_fdot2(pp, v0.h[c], acc[c], false);
        acc[4 + c]  = __builtin_amdgcn_fdot2(pp, v1.h[c], acc[4 + c], false);
        acc[8 + c]  = __builtin_amdgcn_fdot2(pp, v2.h[c], acc[8 + c], false);
        acc[12 + c] = __builtin_amdgcn_fdot2(pp, v3.h[c], acc[12 + c], false);
      }
    }
  }
  __syncthreads();
  float* cb = smem;
  cb[(gq * 17 + 16) * 64 + r] = s;
#pragma unroll
  for (int c = 0; c < 16; ++c) cb[(gq * 17 + c) * 64 + r] = acc[c];
  __syncthreads();
  if (gq == 0) {
    float S = 0.f;
#pragma unroll
    for (int g2 = 0; g2 < 4; ++g2) S += cb[(g2 * 17 + 16) * 64 + r];
    atomAddF(&accS[h * N_NODE + i], S);
#pragma unroll
    for (int c = 0; c < 16; ++c) {
      float A = 0.f;
#pragma unroll
      for (int g2 = 0; g2 < 4; ++g2) A += cb[(g2 * 17 + c) * 64 + r];
      atomAddF(&accO[(h * 16 + c) * N_NODE + i], A);
    }
  }
}

// ---------------- global mean pool (bn3+relu inline) ----------------
__global__ void pool_kernel(const float* __restrict__ z3, const float* __restrict__ st,
                            const float* __restrict__ g, const float* __restrict__ b,
                            const int* __restrict__ batch, float* __restrict__ pool,
                            float* __restrict__ pcnt) {
  int idx = blockIdx.x * blockDim.x + threadIdx.x;
  if (idx >= N_NODE * DD) return;
  int i = idx >> 6, d = idx & 63;
  float v = bn_eval(z3[idx], st, g, b, d, true);
  int gg = batch[i];
  atomAddF(&pool[gg * DD + d], v);
  if (d == 0) atomAddF(&pcnt[gg], 1.0f);
}

// ---------------- final linear + log_softmax ----------------
__global__ void final_kernel(const float* __restrict__ pool, const float* __restrict__ pcnt,
                             const float* __restrict__ fw, const float* __restrict__ fb,
                             float* __restrict__ out) {
  int g = blockIdx.x;
  int d = threadIdx.x;
  __shared__ float mean[64];
  __shared__ float lg[16];
  float c = fmaxf(pcnt[g], 1.0f);
  mean[d] = pool[g * DD + d] / c;
  __syncthreads();
  if (d < 10) {
    float acc = fb[d];
#pragma unroll 8
    for (int k = 0; k < 64; ++k) acc += mean[k] * fw[k * 10 + d];
    lg[d] = acc;
  }
  __syncthreads();
  if (d == 0) {
    float mx = -INFINITY;
    for (int c2 = 0; c2 < 10; ++c2) mx = fmaxf(mx, lg[c2]);
    float sum = 0.f;
    for (int c2 = 0; c2 < 10; ++c2) sum += expf(lg[c2] - mx);
    lg[10] = mx + logf(sum);
  }
  __syncthreads();
  if (d < 10) out[g * 10 + d] = lg[d] - lg[10];
}

extern "C" void kernel_launch(void* const* d_in, const int* in_sizes, int n_in,
                              void* d_out, int out_size, void* d_ws, size_t ws_size,
                              hipStream_t stream) {
  const float* x_in      = (const float*)d_in[0];
  const int*   edge_idx  = (const int*)d_in[1];
  const int*   batch     = (const int*)d_in[2];
  const float* pre_w1    = (const float*)d_in[3];
  const float* pre_b1    = (const float*)d_in[4];
  const float* pre_w2    = (const float*)d_in[5];
  const float* pre_b2    = (const float*)d_in[6];
  const float* gat_wl    = (const float*)d_in[7];
  const float* gat_bl    = (const float*)d_in[8];
  const float* gat_wr    = (const float*)d_in[9];
  const float* gat_br    = (const float*)d_in[10];
  const float* gat_att   = (const float*)d_in[11];
  const float* gat_bias  = (const float*)d_in[12];
  const float* attn_in_w = (const float*)d_in[13];
  const float* attn_in_b = (const float*)d_in[14];
  const float* attn_out_w= (const float*)d_in[15];
  const float* attn_out_b= (const float*)d_in[16];
  const float* bn1_g     = (const float*)d_in[17];
  const float* bn1_b     = (const float*)d_in[18];
  const float* bn2_g     = (const float*)d_in[19];
  const float* bn2_b     = (const float*)d_in[20];
  const float* bn3_g     = (const float*)d_in[21];
  const float* bn3_b     = (const float*)d_in[22];
  const float* mlp_w1    = (const float*)d_in[23];
  const float* mlp_b1    = (const float*)d_in[24];
  const float* mlp_w2    = (const float*)d_in[25];
  const float* mlp_b2    = (const float*)d_in[26];
  const float* fin_w     = (const float*)d_in[27];
  const float* fin_b     = (const float*)d_in[28];
  float* out = (float*)d_out;

  // workspace layout (floats)
  float* ws    = (float*)d_ws;
  float* xbuf  = ws;                    // 262144 (pre output = state0)
  float* xlr   = xbuf + 262144;         // 524288 (pre1 hid; then xl|xr)
  float* qkv   = xlr + 524288;          // 786432 (also mlp hid alias)
  float* hid   = qkv;                   // alias: lifetime disjoint
  float* z1    = qkv + 786432;          // 262144
  float* z2    = z1 + 262144;           // 262144
  float* zA    = z2 + 262144;           // 262144
  float* zB    = zA + 262144;           // 262144
  float* cw    = zB + 262144;           // 61440
  float* cbias = cw + 61440;            // 960
  float* tout  = cbias + 960;           // 12288
  float* st1   = tout + 12288;          // 128
  float* st2   = st1 + 128;             // 128
  float* st3   = st2 + 128;             // 128
  float* st1p  = st3 + 128;             // 32768 (st3p aliases st1p)
  float* st3p  = st1p;
  float* st2p  = st1p + 32768;          // 32768
  // ---- contiguous zero region ----
  float* zr    = st2p + 32768;
  int*   cnt   = (int*)zr;              // 4096
  float* pool  = zr + 4096;             // 4096
  float* pcnt  = pool + 4096;           // 64
  int*   kmax  = (int*)(pcnt + 64);     // 4
  float* accS  = (float*)(kmax + 4);    // 16384
  float* accO  = accS + 16384;          // 262144
  size_t zr_elems = 4096 + 4096 + 64 + 4 + 16384 + 262144;
  float* zend  = accO + 262144;
  int* row_ptr = (int*)zend;            // 4097
  int* nextp   = row_ptr + 4097;        // 4096
  int* csr_src = nextp + 4096;          // 266240

  hipMemsetAsync(zr, 0, zr_elems * sizeof(float), stream);

  // ---- CSR build ----
  hipLaunchKernelGGL(csr_count_kernel, dim3((E_TOT + 255) / 256), dim3(256), 0, stream,
                     edge_idx, cnt);
  hipLaunchKernelGGL(csr_scan_kernel, dim3(1), dim3(256), 0, stream, cnt, row_ptr, nextp);
  hipLaunchKernelGGL(csr_fill_kernel, dim3((E_TOT + 255) / 256), dim3(256), 0, stream,
                     edge_idx, nextp, csr_src);

  // ---- combined weights (once) ----
  hipLaunchKernelGGL(build_w_kernel, dim3((NL * 64 * 320 + 255) / 256), dim3(256), 0, stream,
                     gat_wl, gat_bl, gat_wr, gat_br, attn_in_w, attn_in_b, attn_out_w,
                     cw, cbias, tout);

  // ---- preprocess MLP ----
  {
    LinP p = {}; p.A = x_in; p.W = pre_w1; p.bias = pre_b1; p.C = xlr;
    hipLaunchKernelGGL((lin_kernel<128, 9, 0, 0, 1, false, false, false>),
                       dim3(256), dim3(256), 0, stream, p);
  }
  {
    LinP p = {}; p.A = xlr; p.W = pre_w2; p.bias = pre_b2; p.C = xbuf;
    hipLaunchKernelGGL((lin_kernel<64, 128, 0, 0, 1, false, false, false>),
                       dim3(256), dim3(256), 0, stream, p);
  }

  const float* state = xbuf;
  const float* sstat = nullptr;  // bn3 stats/params of producing layer (null for pre output)
  const float* sg = nullptr;
  const float* sb = nullptr;

  for (int l = 0; l < NL; ++l) {
    float* zcur = (l & 1) ? zB : zA;

    // 1. fused xl|xr|qkv linear (bn3-inline on input state)
    {
      LinP p = {}; p.A = state; p.W = cw + l * 20480; p.bias = cbias + l * 320;
      p.C = xlr; p.C2 = qkv;
      p.i_st = sstat; p.i_g = sg; p.i_b = sb;
      hipLaunchKernelGGL((lin_kernel<320, 64, 1, 0, 0, true, false, false>),
                         dim3(256), dim3(320), 0, stream, p);
    }
    // 2. knorm
    hipLaunchKernelGGL(knorm_kernel, dim3(64), dim3(256), 0, stream, qkv, kmax);
    // 3. attention (accumulates into accS/accO, zeroed by memset or prev outproj)
    hipLaunchKernelGGL(attn_kernel, dim3(N_NODE / 64, 4, 8), dim3(256), 0, stream,
                       qkv, kmax, accS, accO);
    // 4. GATv2 aggregate -> z1 (+ st1 partials)
    hipLaunchKernelGGL(gat_agg_kernel, dim3(256), dim3(1024), 0, stream,
                       state, sstat, sg, sb, xlr, gat_att + l * DD, gat_bias + l * DD,
                       row_ptr, csr_src, z1, st1p);
    // 5. out-proj: A = attn-normalized accO/accS (self-clean), resid bn3(state) -> z2 (+ st2p)
    {
      LinP p = {}; p.W = tout + l * 4096; p.bias = attn_out_b + l * DD; p.C = z2;
      p.accO_w = accO; p.accS_w = accS; p.kmax_clr = kmax;
      p.R = state; p.r_st = sstat; p.r_g = sg; p.r_b = sb;
      p.spart = st2p;
      hipLaunchKernelGGL((lin_kernel<64, 64, 3, 1, 0, false, true, true>),
                         dim3(256), dim3(256), 0, stream, p);
    }
    // 6. reduce st1, st2
    hipLaunchKernelGGL(red_kernel, dim3(128, 2), dim3(64), 0, stream, st1p, st1, st2p, st2);
    // 7. mlp1: A = bn1(z1)+bn2(z2), relu -> hid
    {
      LinP p = {}; p.A = z1; p.A2 = z2; p.W = mlp_w1 + l * 8192; p.bias = mlp_b1 + l * 128;
      p.C = hid;
      p.i_st = st1; p.i_g = bn1_g + l * DD; p.i_b = bn1_b + l * DD;
      p.i2_st = st2; p.i2_g = bn2_g + l * DD; p.i2_b = bn2_b + l * DD;
      hipLaunchKernelGGL((lin_kernel<128, 64, 2, 0, 2, false, false, false>),
                         dim3(256), dim3(256), 0, stream, p);
    }
    // 8. mlp2: A = hid, resid = bn1(z1)+bn2(z2) -> z3 (+ st3p)
    {
      LinP p = {}; p.A = hid; p.W = mlp_w2 + l * 8192; p.bias = mlp_b2 + l * DD; p.C = zcur;
      p.R = z1; p.r_st = st1; p.r_g = bn1_g + l * DD; p.r_b = bn1_b + l * DD;
      p.R2 = z2; p.r2_st = st2; p.r2_g = bn2_g + l * DD; p.r2_b = bn2_b + l * DD;
      p.spart = st3p;
      hipLaunchKernelGGL((lin_kernel<64, 128, 0, 2, 0, false, true, false>),
                         dim3(256), dim3(256), 0, stream, p);
    }
    // 9. reduce st3 (second pair unused; pass distinct ptrs to honor __restrict__)
    hipLaunchKernelGGL(red_kernel, dim3(128, 1), dim3(64), 0, stream, st3p, st3, st2p, st2);

    state = zcur;
    sstat = st3;
    sg = bn3_g + l * DD;
    sb = bn3_b + l * DD;
  }

  // ---- pool (bn3-inline) + final ----
  hipLaunchKernelGGL(pool_kernel, dim3(N_NODE * DD / 256), dim3(256), 0, stream,
                     state, sstat, sg, sb, batch, pool, pcnt);
  hipLaunchKernelGGL(final_kernel, dim3(NG), dim3(64), 0, stream, pool, pcnt, fin_w, fin_b, out);
}